// Round 6
// baseline (637.297 us; speedup 1.0000x reference)
//
#include <hip/hip_runtime.h>
#include <hip/hip_bf16.h>
#include <math.h>

#define NN 50000
#define EE 400000
#define D_IN 256
#define D_H 64
#define N_CLS 50

typedef __attribute__((ext_vector_type(8))) short bfrag;   // 8 bf16 (4 VGPR)
typedef __attribute__((ext_vector_type(4))) float ffrag;   // MFMA C/D
typedef __attribute__((ext_vector_type(8))) unsigned short u16x8_t;
typedef __attribute__((ext_vector_type(4))) unsigned short u16x4_t;

__device__ __forceinline__ unsigned short f2bf(float v) {
    unsigned int u = __float_as_uint(v);
    unsigned int r = (u + 0x7fffu + ((u >> 16) & 1u)) >> 16;   // RNE
    return (unsigned short)r;
}
__device__ __forceinline__ float bf2f(unsigned short b) {
    return __uint_as_float(((unsigned int)b) << 16);
}

// async global->LDS, 16B per lane; lds dst is wave-uniform base + lane*16
__device__ __forceinline__ void gl_lds16(const unsigned short* g, unsigned short* l) {
    __builtin_amdgcn_global_load_lds(
        (__attribute__((address_space(1))) void*)(unsigned short*)g,
        (__attribute__((address_space(3))) void*)l,
        16, 0, 0);
}

// ---------------------------------------------------------------------------
// CSR construction (verified round 0)
// ---------------------------------------------------------------------------
__global__ void zero_k(int* p, int n) {
    int i = blockIdx.x * blockDim.x + threadIdx.x;
    if (i < n) p[i] = 0;
}

__global__ void count_k(const int* __restrict__ ei, int* __restrict__ cnt, int E, int N) {
    int i = blockIdx.x * blockDim.x + threadIdx.x;
    if (i >= E + N) return;
    int dst = (i < E) ? ei[E + i] : (i - E);
    atomicAdd(&cnt[dst], 1);
}

__global__ __launch_bounds__(1024) void scan_k(const int* __restrict__ counts,
                                               int* __restrict__ rowptr, int n) {
    __shared__ int wsum[16];
    __shared__ int carry_s;
    int t = threadIdx.x;
    int lane = t & 63, wid = t >> 6;
    if (t == 0) carry_s = 0;
    __syncthreads();
    for (int base = 0; base < n; base += 1024) {
        int idx = base + t;
        int v = (idx < n) ? counts[idx] : 0;
        int incl = v;
        #pragma unroll
        for (int off = 1; off < 64; off <<= 1) {
            int x = __shfl_up(incl, off);
            if (lane >= off) incl += x;
        }
        if (lane == 63) wsum[wid] = incl;
        __syncthreads();
        if (wid == 0) {
            int ws = (lane < 16) ? wsum[lane] : 0;
            int wincl = ws;
            #pragma unroll
            for (int off = 1; off < 16; off <<= 1) {
                int x = __shfl_up(wincl, off);
                if (lane >= off) wincl += x;
            }
            if (lane < 16) wsum[lane] = wincl - ws;
        }
        __syncthreads();
        int c = carry_s;
        if (idx < n) rowptr[idx] = c + wsum[wid] + (incl - v);
        __syncthreads();
        if (t == 1023) carry_s = c + wsum[15] + incl;
        __syncthreads();
    }
    if (t == 0) rowptr[n] = carry_s;
}

__global__ void fill_k(const int* __restrict__ ei, const int* __restrict__ rowptr,
                       int* __restrict__ cursor, int* __restrict__ csr, int E, int N) {
    int i = blockIdx.x * blockDim.x + threadIdx.x;
    if (i >= E + N) return;
    int s, d;
    if (i < E) { s = ei[i]; d = ei[E + i]; }
    else       { s = i - E; d = i - E; }
    int pos = atomicAdd(&cursor[d], 1);
    csr[rowptr[d] + pos] = s;
}

// ---------------------------------------------------------------------------
// Extended-K conversions: A -> [hi | lo | hi], B[K][N] -> BT_ext[N][3K] =
// [hi | hi | lo]. Sum over KE reproduces hi*hi + lo*hi + hi*lo exactly.
// ---------------------------------------------------------------------------
__global__ void cvt_a3_k(const float* __restrict__ a, unsigned short* __restrict__ ext,
                         int M, int K) {
    int i = blockIdx.x * 256 + threadIdx.x;
    if (i >= M * K) return;
    int r = i / K, c = i - r * K;
    float v = a[i];
    unsigned short h = f2bf(v);
    unsigned short l = f2bf(v - bf2f(h));
    size_t b = (size_t)r * (3 * K) + c;
    ext[b] = h; ext[b + K] = l; ext[b + 2 * K] = h;
}

__global__ void cvt_bt3_k(const float* __restrict__ B, unsigned short* __restrict__ ext,
                          int K, int N) {
    int i = blockIdx.x * 256 + threadIdx.x;
    if (i >= K * N) return;
    int k = i / N, n = i - k * N;
    float v = B[i];
    unsigned short h = f2bf(v);
    unsigned short l = f2bf(v - bf2f(h));
    size_t b = (size_t)n * (3 * K) + k;
    ext[b] = h; ext[b + K] = h; ext[b + 2 * K] = l;
}

// BN folding: scale = g*rsqrt(v+eps); shift = (bias - m)*scale + b
__global__ void bnprep_k(const float* __restrict__ g, const float* __restrict__ b,
                         const float* __restrict__ m, const float* __restrict__ v,
                         const float* __restrict__ bias,
                         float* __restrict__ scale, float* __restrict__ shift) {
    int t = threadIdx.x;
    if (t < 64) {
        float sc = g[t] * rsqrtf(v[t] + 1e-5f);
        scale[t] = sc;
        shift[t] = (bias[t] - m[t]) * sc + b[t];
    }
}

// ---------------------------------------------------------------------------
// Standard bf16 MFMA GEMM on extended-K operands (m97 recipe):
// 128x128 tile, BK=32, global_load_lds width-16 staging, XOR-swizzled
// unpadded LDS (2-way bank alias = free). 4 waves in 2x2; wave tile 64x64 =
// 4x4 of 16x16x32 MFMAs. Epilogues: fp32 C / bf16 C / split-ext C,
// bias+ReLU, fused per-head attention scores.
// ---------------------------------------------------------------------------
__global__ __launch_bounds__(256) void gemm_ext_k(
    const unsigned short* __restrict__ Aext,   // [M][KE]
    const unsigned short* __restrict__ BTe,    // [N][KE]
    float* __restrict__ Cf, unsigned short* __restrict__ Chi,
    unsigned short* __restrict__ Cext,         // [M][3N] split ext out
    int M, int N, int KE,
    const float* __restrict__ bias, int do_relu,
    const float* __restrict__ att_s, const float* __restrict__ att_d,
    float* __restrict__ asb, float* __restrict__ adb, int H) {
    __shared__ unsigned short sA[128 * 32];
    __shared__ unsigned short sB[128 * 32];
    const int tid = threadIdx.x;
    const int lane = tid & 63, w = tid >> 6;
    const int wm = w >> 1, wn = w & 1;
    const int c16 = lane & 15, kq = lane >> 4;
    const int m0 = blockIdx.y * 128;
    const int n0 = blockIdx.x * 128;
    // staging: each wave stages chunks 2w and 2w+1 (16 rows x 32 cols each)
    const int rl = lane >> 2, sl = lane & 3;
    const int rt0 = (2 * w) * 16 + rl;
    const int rt1 = (2 * w + 1) * 16 + rl;
    const int sub0 = sl ^ ((rt0 >> 1) & 3);
    const int sub1 = sl ^ ((rt1 >> 1) & 3);
    const size_t arow0 = (size_t)min(m0 + rt0, M - 1) * KE;
    const size_t arow1 = (size_t)min(m0 + rt1, M - 1) * KE;
    const size_t brow0 = (size_t)min(n0 + rt0, N - 1) * KE;
    const size_t brow1 = (size_t)min(n0 + rt1, N - 1) * KE;
    unsigned short* lA0 = &sA[(2 * w) * 512];
    unsigned short* lA1 = &sA[(2 * w + 1) * 512];
    unsigned short* lB0 = &sB[(2 * w) * 512];
    unsigned short* lB1 = &sB[(2 * w + 1) * 512];
    // fragment LDS offsets (swizzle-consistent with staging)
    int aoff[4], boff[4];
    #pragma unroll
    for (int t = 0; t < 4; t++) {
        int ra = wm * 64 + t * 16 + c16;
        aoff[t] = ra * 32 + ((kq ^ ((ra >> 1) & 3)) << 3);
        int rb = wn * 64 + t * 16 + c16;
        boff[t] = rb * 32 + ((kq ^ ((rb >> 1) & 3)) << 3);
    }
    ffrag acc[4][4] = {};

    for (int k0 = 0; k0 < KE; k0 += 32) {
        __syncthreads();
        gl_lds16(Aext + arow0 + k0 + sub0 * 8, lA0);
        gl_lds16(Aext + arow1 + k0 + sub1 * 8, lA1);
        gl_lds16(BTe + brow0 + k0 + sub0 * 8, lB0);
        gl_lds16(BTe + brow1 + k0 + sub1 * 8, lB1);
        __syncthreads();
        bfrag af[4], bf[4];
        #pragma unroll
        for (int t = 0; t < 4; t++) af[t] = *(const bfrag*)&sA[aoff[t]];
        #pragma unroll
        for (int t = 0; t < 4; t++) bf[t] = *(const bfrag*)&sB[boff[t]];
        #pragma unroll
        for (int mt = 0; mt < 4; mt++)
            #pragma unroll
            for (int nt = 0; nt < 4; nt++)
                acc[mt][nt] = __builtin_amdgcn_mfma_f32_16x16x32_bf16(af[mt], bf[nt], acc[mt][nt], 0, 0, 0);
    }

    // ---- fused attention scores (raw h; GAT layers). wave cols = one head ----
    if (att_s) {
        int hidx = (n0 >> 6) + wn;
        if (hidx < H) {
            float s_att[4], d_att[4];
            #pragma unroll
            for (int nt = 0; nt < 4; nt++) {
                s_att[nt] = att_s[hidx * 64 + nt * 16 + c16];
                d_att[nt] = att_d[hidx * 64 + nt * 16 + c16];
            }
            #pragma unroll
            for (int mt = 0; mt < 4; mt++) {
                #pragma unroll
                for (int r = 0; r < 4; r++) {
                    int row = m0 + wm * 64 + mt * 16 + kq * 4 + r;
                    float ps = 0.f, pd = 0.f;
                    #pragma unroll
                    for (int nt = 0; nt < 4; nt++) {
                        ps = fmaf(acc[mt][nt][r], s_att[nt], ps);
                        pd = fmaf(acc[mt][nt][r], d_att[nt], pd);
                    }
                    #pragma unroll
                    for (int msk = 1; msk < 16; msk <<= 1) {
                        ps += __shfl_xor(ps, msk);
                        pd += __shfl_xor(pd, msk);
                    }
                    if (c16 == 0 && row < M) {
                        asb[(size_t)row * H + hidx] = ps;
                        adb[(size_t)row * H + hidx] = pd;
                    }
                }
            }
        }
    }

    // ---- C write ----
    #pragma unroll
    for (int mt = 0; mt < 4; mt++) {
        #pragma unroll
        for (int r = 0; r < 4; r++) {
            int row = m0 + wm * 64 + mt * 16 + kq * 4 + r;
            if (row >= M) continue;
            #pragma unroll
            for (int nt = 0; nt < 4; nt++) {
                int col = n0 + wn * 64 + nt * 16 + c16;
                if (col >= N) continue;
                float v = acc[mt][nt][r];
                if (bias) v += bias[col];
                if (do_relu) v = fmaxf(v, 0.f);
                if (Cf) Cf[(size_t)row * N + col] = v;
                if (Chi) Chi[(size_t)row * N + col] = f2bf(v);
                if (Cext) {
                    unsigned short hh = f2bf(v);
                    unsigned short ll = f2bf(v - bf2f(hh));
                    size_t b = (size_t)row * (3 * N);
                    Cext[b + col] = hh;
                    Cext[b + N + col] = ll;
                    Cext[b + 2 * N + col] = hh;
                }
            }
        }
    }
}

__device__ __forceinline__ float wave_max_f(float v) {
    #pragma unroll
    for (int off = 32; off; off >>= 1) v = fmaxf(v, __shfl_xor(v, off));
    return v;
}
__device__ __forceinline__ float wave_sum_f(float v) {
    #pragma unroll
    for (int off = 32; off; off >>= 1) v += __shfl_xor(v, off);
    return v;
}

// ---------------------------------------------------------------------------
// Aggregation (verified round 5): one wave per node, all heads, bf16 gather.
// Output written in split-ext layout [hi | lo | hi] (stride 192) to feed the
// next extended-K GEMM directly.
// ---------------------------------------------------------------------------
template <int H, bool MEAN_BN>
__global__ __launch_bounds__(256) void agg_k(
    const unsigned short* __restrict__ hfeat,   // [N, H*64] bf16
    const float* __restrict__ a_s, const float* __restrict__ a_d,
    const int* __restrict__ rowptr, const int* __restrict__ csr,
    const float* __restrict__ scale,   // MEAN_BN: folded BN scale; else unused
    const float* __restrict__ shift,   // MEAN_BN: folded BN shift; else bias
    unsigned short* __restrict__ outext, int N) {
    constexpr int OUT = H * 64;
    constexpr int F = H;
    constexpr int G = 64 / H;
    __shared__ float alpha_s[4][H][65];
    const int wv = threadIdx.x >> 6;
    const int lane = threadIdx.x & 63;
    const int node = blockIdx.x * 4 + wv;
    if (node >= N) return;        // no __syncthreads in this kernel — safe

    const int row = rowptr[node];
    const int deg = rowptr[node + 1] - row;
    const int hl = lane / G;

    float adn[H];
    #pragma unroll
    for (int h = 0; h < H; h++) adn[h] = a_d[(size_t)node * H + h];

    float acc[F] = {};

    if (deg <= 64) {
        int s = 0;
        float e[H];
        #pragma unroll
        for (int h = 0; h < H; h++) e[h] = -INFINITY;
        if (lane < deg) {
            s = csr[row + lane];
            const float* ap = a_s + (size_t)s * H;
            if constexpr (H >= 4) {
                #pragma unroll
                for (int h4 = 0; h4 < H; h4 += 4) {
                    float4 av = *(const float4*)(ap + h4);
                    e[h4 + 0] = av.x + adn[h4 + 0];
                    e[h4 + 1] = av.y + adn[h4 + 1];
                    e[h4 + 2] = av.z + adn[h4 + 2];
                    e[h4 + 3] = av.w + adn[h4 + 3];
                }
            } else {
                e[0] = ap[0] + adn[0];
            }
            #pragma unroll
            for (int h = 0; h < H; h++) e[h] = e[h] > 0.f ? e[h] : 0.2f * e[h];
        }
        float m[H], p[H], inv[H];
        #pragma unroll
        for (int h = 0; h < H; h++) m[h] = wave_max_f(e[h]);
        #pragma unroll
        for (int h = 0; h < H; h++) p[h] = (lane < deg) ? __expf(e[h] - m[h]) : 0.f;
        #pragma unroll
        for (int h = 0; h < H; h++) inv[h] = 1.f / (wave_sum_f(p[h]) + 1e-16f);
        if (lane < deg) {
            #pragma unroll
            for (int h = 0; h < H; h++) alpha_s[wv][h][lane] = p[h] * inv[h];
        }
        asm volatile("s_waitcnt lgkmcnt(0)" ::: "memory");
        for (int jj = 0; jj < deg; jj++) {
            int ss = __builtin_amdgcn_readlane(s, jj);
            float al = alpha_s[wv][hl][jj];
            const unsigned short* rp = hfeat + (size_t)ss * OUT + lane * F;
            if constexpr (F == 8) {
                u16x8_t u = *(const u16x8_t*)rp;
                #pragma unroll
                for (int i = 0; i < 8; i++) acc[i] = fmaf(al, bf2f(u[i]), acc[i]);
            } else if constexpr (F == 4) {
                u16x4_t u = *(const u16x4_t*)rp;
                #pragma unroll
                for (int i = 0; i < 4; i++) acc[i] = fmaf(al, bf2f(u[i]), acc[i]);
            } else {
                acc[0] = fmaf(al, bf2f(rp[0]), acc[0]);
            }
        }
    } else {
        float m[H];
        #pragma unroll
        for (int h = 0; h < H; h++) m[h] = -INFINITY;
        for (int c0 = 0; c0 < deg; c0 += 64) {
            int j = c0 + lane;
            if (j < deg) {
                int s2 = csr[row + j];
                #pragma unroll
                for (int h = 0; h < H; h++) {
                    float e = a_s[(size_t)s2 * H + h] + adn[h];
                    e = e > 0.f ? e : 0.2f * e;
                    m[h] = fmaxf(m[h], e);
                }
            }
        }
        #pragma unroll
        for (int h = 0; h < H; h++) m[h] = wave_max_f(m[h]);
        float dsum[H] = {};
        for (int c0 = 0; c0 < deg; c0 += 64) {
            int j = c0 + lane;
            if (j < deg) {
                int s2 = csr[row + j];
                #pragma unroll
                for (int h = 0; h < H; h++) {
                    float e = a_s[(size_t)s2 * H + h] + adn[h];
                    e = e > 0.f ? e : 0.2f * e;
                    dsum[h] += __expf(e - m[h]);
                }
            }
        }
        float inv[H];
        #pragma unroll
        for (int h = 0; h < H; h++) inv[h] = 1.f / (wave_sum_f(dsum[h]) + 1e-16f);
        for (int c0 = 0; c0 < deg; c0 += 64) {
            int j = c0 + lane;
            int cnt = min(64, deg - c0);
            int s = 0;
            if (j < deg) {
                s = csr[row + j];
                #pragma unroll
                for (int h = 0; h < H; h++) {
                    float e = a_s[(size_t)s * H + h] + adn[h];
                    e = e > 0.f ? e : 0.2f * e;
                    alpha_s[wv][h][lane] = __expf(e - m[h]) * inv[h];
                }
            }
            asm volatile("s_waitcnt lgkmcnt(0)" ::: "memory");
            for (int jj = 0; jj < cnt; jj++) {
                int ss = __builtin_amdgcn_readlane(s, jj);
                float al = alpha_s[wv][hl][jj];
                const unsigned short* rp = hfeat + (size_t)ss * OUT + lane * F;
                if constexpr (F == 8) {
                    u16x8_t u = *(const u16x8_t*)rp;
                    #pragma unroll
                    for (int i = 0; i < 8; i++) acc[i] = fmaf(al, bf2f(u[i]), acc[i]);
                } else if constexpr (F == 4) {
                    u16x4_t u = *(const u16x4_t*)rp;
                    #pragma unroll
                    for (int i = 0; i < 4; i++) acc[i] = fmaf(al, bf2f(u[i]), acc[i]);
                } else {
                    acc[0] = fmaf(al, bf2f(rp[0]), acc[0]);
                }
            }
            asm volatile("s_waitcnt lgkmcnt(0)" ::: "memory");
        }
    }

    if constexpr (MEAN_BN) {
        #pragma unroll
        for (int i = 0; i < F; i++) {
            #pragma unroll
            for (int msk = G; msk < 64; msk <<= 1)
                acc[i] += __shfl_xor(acc[i], msk);
        }
        if (lane < G) {
            int c0 = lane * F;
            size_t b = (size_t)node * 192;
            #pragma unroll
            for (int i = 0; i < F; i++) {
                float v = fmaf(acc[i] * (1.0f / H), scale[c0 + i], shift[c0 + i]);
                v = fmaxf(v, 0.f);
                unsigned short hh = f2bf(v);
                unsigned short ll = f2bf(v - bf2f(hh));
                outext[b + c0 + i] = hh;
                outext[b + 64 + c0 + i] = ll;
                outext[b + 128 + c0 + i] = hh;
            }
        }
    } else {
        float v = acc[0] + shift[lane];
        unsigned short hh = f2bf(v);
        unsigned short ll = f2bf(v - bf2f(hh));
        size_t b = (size_t)node * 192;
        outext[b + lane] = hh;
        outext[b + 64 + lane] = ll;
        outext[b + 128 + lane] = hh;
    }
}

// ---------------------------------------------------------------------------
// Softmax over N_CLS logits, wave per node.
// ---------------------------------------------------------------------------
__global__ __launch_bounds__(256) void softmax_k(const float* __restrict__ logits,
                                                 float* __restrict__ out, int N) {
    int lane = threadIdx.x & 63;
    int n = (blockIdx.x * blockDim.x + threadIdx.x) >> 6;
    if (n >= N) return;
    float lg = (lane < N_CLS) ? logits[(size_t)n * N_CLS + lane] : -INFINITY;
    float m = wave_max_f(lg);
    float p = (lane < N_CLS) ? __expf(lg - m) : 0.f;
    float s = wave_sum_f(p);
    if (lane < N_CLS) out[(size_t)n * N_CLS + lane] = p / s;
}

// ---------------------------------------------------------------------------
extern "C" void kernel_launch(void* const* d_in, const int* in_sizes, int n_in,
                              void* d_out, int out_size, void* d_ws, size_t ws_size,
                              hipStream_t stream) {
    const int N = NN, E = EE, E2 = EE + NN;
    const float* x    = (const float*)d_in[0];
    const int*   ei   = (const int*)d_in[1];
    const float* W1   = (const float*)d_in[2];
    const float* as1  = (const float*)d_in[3];
    const float* ad1  = (const float*)d_in[4];
    const float* b1   = (const float*)d_in[5];
    const float* W2   = (const float*)d_in[6];
    const float* as2  = (const float*)d_in[7];
    const float* ad2  = (const float*)d_in[8];
    const float* b2   = (const float*)d_in[9];
    const float* W3   = (const float*)d_in[10];
    const float* as3  = (const float*)d_in[11];
    const float* ad3  = (const float*)d_in[12];
    const float* b3   = (const float*)d_in[13];
    const float* bn1g = (const float*)d_in[14];
    const float* bn1b = (const float*)d_in[15];
    const float* bn1m = (const float*)d_in[16];
    const float* bn1v = (const float*)d_in[17];
    const float* bn2g = (const float*)d_in[18];
    const float* bn2b = (const float*)d_in[19];
    const float* bn2m = (const float*)d_in[20];
    const float* bn2v = (const float*)d_in[21];
    const float* cW1  = (const float*)d_in[22];
    const float* cb1  = (const float*)d_in[23];
    const float* cW2  = (const float*)d_in[24];
    const float* cb2  = (const float*)d_in[25];
    float* out = (float*)d_out;

    char* ws = (char*)d_ws;
    size_t off = 0;
    auto alloc = [&](size_t bytes) {
        void* p = ws + off;
        off = (off + bytes + 255) & ~(size_t)255;
        return p;
    };
    int*   rowptr = (int*)alloc((size_t)(N + 1) * 4);
    int*   cursor = (int*)alloc((size_t)N * 4);
    int*   csr    = (int*)alloc((size_t)E2 * 4);
    unsigned short* xext = (unsigned short*)alloc((size_t)N * 768 * 2);   // 76.8 MB
    unsigned short* hbf  = (unsigned short*)alloc((size_t)N * 512 * 2);   // 51.2 MB
    float* asb    = (float*)alloc((size_t)N * 8 * 4);
    float* adb    = (float*)alloc((size_t)N * 8 * 4);
    unsigned short* f1ext = (unsigned short*)alloc((size_t)N * 192 * 2);
    unsigned short* f2ext = (unsigned short*)alloc((size_t)N * 192 * 2);
    unsigned short* wext  = (unsigned short*)alloc((size_t)512 * 768 * 2);
    float* sc1 = (float*)alloc(64 * 4);
    float* sh1 = (float*)alloc(64 * 4);
    float* sc2 = (float*)alloc(64 * 4);
    float* sh2 = (float*)alloc(64 * 4);
    // aliases (stream-ordered, regions free by then):
    unsigned short* f3ext = f2ext;           // f2ext free after L3 gemm; agg L3 runs after
    unsigned short* zext  = f1ext;           // f1ext free after L2 gemm
    float* logits = (float*)xext;            // xext free after L1 gemm

    // ---- CSR build + BN fold ----
    zero_k<<<(N + 255) / 256, 256, 0, stream>>>(cursor, N);
    count_k<<<(E2 + 255) / 256, 256, 0, stream>>>(ei, cursor, E, N);
    scan_k<<<1, 1024, 0, stream>>>(cursor, rowptr, N);
    zero_k<<<(N + 255) / 256, 256, 0, stream>>>(cursor, N);
    fill_k<<<(E2 + 255) / 256, 256, 0, stream>>>(ei, rowptr, cursor, csr, E, N);
    bnprep_k<<<1, 64, 0, stream>>>(bn1g, bn1b, bn1m, bn1v, b1, sc1, sh1);
    bnprep_k<<<1, 64, 0, stream>>>(bn2g, bn2b, bn2m, bn2v, b2, sc2, sh2);

    const int MB = (N + 127) / 128;          // 391
    const int AB = (N + 3) / 4;

    // ---- Layer 1: heads=8, in=256 (KE=768) ----
    cvt_a3_k<<<((size_t)N * 256 + 255) / 256, 256, 0, stream>>>(x, xext, N, 256);
    cvt_bt3_k<<<(256 * 512 + 255) / 256, 256, 0, stream>>>(W1, wext, 256, 512);
    gemm_ext_k<<<dim3(4, MB), 256, 0, stream>>>(xext, wext, nullptr, hbf, nullptr,
        N, 512, 768, nullptr, 0, as1, ad1, asb, adb, 8);
    agg_k<8, true><<<AB, 256, 0, stream>>>(hbf, asb, adb, rowptr, csr, sc1, sh1, f1ext, N);

    // ---- Layer 2: heads=4, in=64 (KE=192) ----
    cvt_bt3_k<<<(64 * 256 + 255) / 256, 256, 0, stream>>>(W2, wext, 64, 256);
    gemm_ext_k<<<dim3(2, MB), 256, 0, stream>>>(f1ext, wext, nullptr, hbf, nullptr,
        N, 256, 192, nullptr, 0, as2, ad2, asb, adb, 4);
    agg_k<4, true><<<AB, 256, 0, stream>>>(hbf, asb, adb, rowptr, csr, sc2, sh2, f2ext, N);

    // ---- Layer 3: heads=1, in=64, concat (KE=192) ----
    cvt_bt3_k<<<(64 * 64 + 255) / 256, 256, 0, stream>>>(W3, wext, 64, 64);
    gemm_ext_k<<<dim3(1, MB), 256, 0, stream>>>(f2ext, wext, nullptr, hbf, nullptr,
        N, 64, 192, nullptr, 0, as3, ad3, asb, adb, 1);
    agg_k<1, false><<<AB, 256, 0, stream>>>(hbf, asb, adb, rowptr, csr, nullptr, b3, f3ext, N);

    // ---- Classifier: z = relu(f3@cW1+cb1) (ext out); logits; softmax ----
    cvt_bt3_k<<<(64 * 64 + 255) / 256, 256, 0, stream>>>(cW1, wext, 64, 64);
    gemm_ext_k<<<dim3(1, MB), 256, 0, stream>>>(f3ext, wext, nullptr, nullptr, zext,
        N, 64, 192, cb1, 1, nullptr, nullptr, nullptr, nullptr, 0);
    cvt_bt3_k<<<(64 * N_CLS + 255) / 256, 256, 0, stream>>>(cW2, wext, 64, N_CLS);
    gemm_ext_k<<<dim3(1, MB), 256, 0, stream>>>(zext, wext, logits, nullptr, nullptr,
        N, N_CLS, 192, cb2, 0, nullptr, nullptr, nullptr, nullptr, 0);
    softmax_k<<<(N + 3) / 4, 256, 0, stream>>>(logits, out, N);
}

// Round 7
// 591.441 us; speedup vs baseline: 1.0775x; 1.0775x over previous
//
#include <hip/hip_runtime.h>
#include <hip/hip_bf16.h>
#include <math.h>

#define NN 50000
#define EE 400000
#define D_IN 256
#define D_H 64
#define N_CLS 50

typedef __attribute__((ext_vector_type(8))) short bfrag;   // 8 bf16 (4 VGPR)
typedef __attribute__((ext_vector_type(4))) float ffrag;   // MFMA C/D
typedef __attribute__((ext_vector_type(8))) unsigned short u16x8_t;
typedef __attribute__((ext_vector_type(4))) unsigned short u16x4_t;

__device__ __forceinline__ unsigned short f2bf(float v) {
    unsigned int u = __float_as_uint(v);
    unsigned int r = (u + 0x7fffu + ((u >> 16) & 1u)) >> 16;   // RNE
    return (unsigned short)r;
}
__device__ __forceinline__ float bf2f(unsigned short b) {
    return __uint_as_float(((unsigned int)b) << 16);
}

// async global->LDS, 16B/lane; LDS dst = wave-uniform base + lane*16 (verified r6)
__device__ __forceinline__ void gl_lds16(const unsigned short* g, unsigned short* l) {
    __builtin_amdgcn_global_load_lds(
        (__attribute__((address_space(1))) void*)(unsigned short*)g,
        (__attribute__((address_space(3))) void*)l,
        16, 0, 0);
}

// ---------------------------------------------------------------------------
// CSR construction — parallel 3-phase scan (replaces serial single-block scan)
// ---------------------------------------------------------------------------
__global__ void zero_k(int* p, int n) {
    int i = blockIdx.x * blockDim.x + threadIdx.x;
    if (i < n) p[i] = 0;
}

__global__ void count_k(const int* __restrict__ ei, int* __restrict__ cnt, int E, int N) {
    int i = blockIdx.x * blockDim.x + threadIdx.x;
    if (i >= E + N) return;
    int dst = (i < E) ? ei[E + i] : (i - E);
    atomicAdd(&cnt[dst], 1);
}

// phase 1: per-1024-block exclusive scan + block totals
__global__ __launch_bounds__(1024) void scan1_k(const int* __restrict__ counts,
                                                int* __restrict__ excl,
                                                int* __restrict__ bsum, int n) {
    __shared__ int wsum[16];
    int t = threadIdx.x;
    int lane = t & 63, wid = t >> 6;
    int idx = blockIdx.x * 1024 + t;
    int v = (idx < n) ? counts[idx] : 0;
    int incl = v;
    #pragma unroll
    for (int off = 1; off < 64; off <<= 1) {
        int x = __shfl_up(incl, off);
        if (lane >= off) incl += x;
    }
    if (lane == 63) wsum[wid] = incl;
    __syncthreads();
    if (wid == 0) {
        int ws = (lane < 16) ? wsum[lane] : 0;
        int wincl = ws;
        #pragma unroll
        for (int off = 1; off < 16; off <<= 1) {
            int x = __shfl_up(wincl, off);
            if (lane >= off) wincl += x;
        }
        if (lane < 16) wsum[lane] = wincl - ws;   // exclusive wave prefix
    }
    __syncthreads();
    if (idx < n) excl[idx] = wsum[wid] + (incl - v);
    if (t == 1023) bsum[blockIdx.x] = wsum[15] + incl;
}

// phase 2: exclusive scan of block sums (nb <= 64, one wave)
__global__ void scan2_k(int* __restrict__ bsum, int nb) {
    int lane = threadIdx.x & 63;
    int v = (lane < nb) ? bsum[lane] : 0;
    int incl = v;
    #pragma unroll
    for (int off = 1; off < 64; off <<= 1) {
        int x = __shfl_up(incl, off);
        if (lane >= off) incl += x;
    }
    if (lane < nb) bsum[lane] = incl - v;
}

// phase 3: combine
__global__ void scan3_k(const int* __restrict__ excl, const int* __restrict__ bsum,
                        int* __restrict__ rowptr, int n, int total) {
    int i = blockIdx.x * 256 + threadIdx.x;
    if (i < n) rowptr[i] = excl[i] + bsum[i >> 10];
    if (i == 0) rowptr[n] = total;
}

__global__ void fill_k(const int* __restrict__ ei, const int* __restrict__ rowptr,
                       int* __restrict__ cursor, int* __restrict__ csr, int E, int N) {
    int i = blockIdx.x * blockDim.x + threadIdx.x;
    if (i >= E + N) return;
    int s, d;
    if (i < E) { s = ei[i]; d = ei[E + i]; }
    else       { s = i - E; d = i - E; }
    int pos = atomicAdd(&cursor[d], 1);
    csr[rowptr[d] + pos] = s;
}

// ---------------------------------------------------------------------------
// Extended-K conversions: A -> [hi | lo | hi], B[K][N] -> BT_ext[N][3K] =
// [hi | hi | lo]. Sum over KE reproduces hi*hi + lo*hi + hi*lo exactly.
// ---------------------------------------------------------------------------
__global__ void cvt_a3_k(const float* __restrict__ a, unsigned short* __restrict__ ext,
                         int M, int K) {
    int i = blockIdx.x * 256 + threadIdx.x;
    if (i >= M * K) return;
    int r = i / K, c = i - r * K;
    float v = a[i];
    unsigned short h = f2bf(v);
    unsigned short l = f2bf(v - bf2f(h));
    size_t b = (size_t)r * (3 * K) + c;
    ext[b] = h; ext[b + K] = l; ext[b + 2 * K] = h;
}

__global__ void cvt_bt3_k(const float* __restrict__ B, unsigned short* __restrict__ ext,
                          int K, int N) {
    int i = blockIdx.x * 256 + threadIdx.x;
    if (i >= K * N) return;
    int k = i / N, n = i - k * N;
    float v = B[i];
    unsigned short h = f2bf(v);
    unsigned short l = f2bf(v - bf2f(h));
    size_t b = (size_t)n * (3 * K) + k;
    ext[b] = h; ext[b + K] = h; ext[b + 2 * K] = l;
}

// BN folding: scale = g*rsqrt(v+eps); shift = (bias - m)*scale + b
__global__ void bnprep_k(const float* __restrict__ g, const float* __restrict__ b,
                         const float* __restrict__ m, const float* __restrict__ v,
                         const float* __restrict__ bias,
                         float* __restrict__ scale, float* __restrict__ shift) {
    int t = threadIdx.x;
    if (t < 64) {
        float sc = g[t] * rsqrtf(v[t] + 1e-5f);
        scale[t] = sc;
        shift[t] = (bias[t] - m[t]) * sc + b[t];
    }
}

// ---------------------------------------------------------------------------
// Full-N-per-block ext-K MFMA GEMM. 512 threads = 8 waves of 64x64 tiles,
// arranged (8>>lognwt) m-tiles x (1<<lognwt) n-tiles; block covers RT rows x
// all N cols -> A fetched once from HBM, B L2-resident. BK=32,
// global_load_lds width-16 staging, XOR-swizzled unpadded LDS (2-way = free).
// Epilogues: fp32 / bf16 / split-ext C, bias+ReLU, fused attention scores.
// ---------------------------------------------------------------------------
__global__ __launch_bounds__(512) void gemm_ext_k(
    const unsigned short* __restrict__ Aext,   // [M][KE]
    const unsigned short* __restrict__ BTe,    // [N][KE]
    float* __restrict__ Cf, unsigned short* __restrict__ Chi,
    unsigned short* __restrict__ Cext,         // [M][3N] split ext out
    int M, int N, int KE, int lognwt,
    const float* __restrict__ bias, int do_relu,
    const float* __restrict__ att_s, const float* __restrict__ att_d,
    float* __restrict__ asb, float* __restrict__ adb) {
    __shared__ unsigned short sbuf[20480];     // 40960 B = 5 DMA rounds max
    const int nwt = 1 << lognwt;
    const int NT = nwt * 64;
    const int RT = 512 >> lognwt;
    const int S_rows = RT + NT;                // 64B rows staged per K-chunk
    const int rounds = (S_rows + 127) >> 7;    // 128 rows per 512-thread round
    const int tid = threadIdx.x;
    const int lane = tid & 63, w = tid >> 6;
    const int mtile = w >> lognwt;
    const int ntile = w & (nwt - 1);
    const int c16 = lane & 15, kq = lane >> 4;
    const int m0 = blockIdx.x * RT;

    // fragment LDS offsets (shorts), swizzle-consistent with staging
    int aoff[4], boff[4];
    #pragma unroll
    for (int t = 0; t < 4; t++) {
        int ra = mtile * 64 + t * 16 + c16;
        aoff[t] = ra * 32 + ((kq ^ ((ra >> 1) & 3)) << 3);
        int rb = RT + ntile * 64 + t * 16 + c16;
        boff[t] = rb * 32 + ((kq ^ ((rb >> 1) & 3)) << 3);
    }
    ffrag acc[4][4] = {};

    for (int k0 = 0; k0 < KE; k0 += 32) {
        __syncthreads();
        for (int rd = 0; rd < rounds; rd++) {
            int row = rd * 128 + w * 16 + (lane >> 2);
            int gsub = (lane & 3) ^ ((row >> 1) & 3);
            const unsigned short* src;
            if (row < RT)
                src = Aext + (size_t)min(m0 + row, M - 1) * KE + k0 + gsub * 8;
            else
                src = BTe + (size_t)min(row - RT, N - 1) * KE + k0 + gsub * 8;
            gl_lds16(src, &sbuf[rd * 4096 + w * 512]);
        }
        __syncthreads();
        bfrag af[4], bf[4];
        #pragma unroll
        for (int t = 0; t < 4; t++) af[t] = *(const bfrag*)&sbuf[aoff[t]];
        #pragma unroll
        for (int t = 0; t < 4; t++) bf[t] = *(const bfrag*)&sbuf[boff[t]];
        #pragma unroll
        for (int mt = 0; mt < 4; mt++)
            #pragma unroll
            for (int nt = 0; nt < 4; nt++)
                acc[mt][nt] = __builtin_amdgcn_mfma_f32_16x16x32_bf16(af[mt], bf[nt], acc[mt][nt], 0, 0, 0);
    }

    // ---- fused attention scores (raw h; GAT layers). ntile == head ----
    if (att_s) {
        int hidx = ntile;
        float s_att[4], d_att[4];
        #pragma unroll
        for (int nt = 0; nt < 4; nt++) {
            s_att[nt] = att_s[hidx * 64 + nt * 16 + c16];
            d_att[nt] = att_d[hidx * 64 + nt * 16 + c16];
        }
        #pragma unroll
        for (int mt = 0; mt < 4; mt++) {
            #pragma unroll
            for (int r = 0; r < 4; r++) {
                int row = m0 + mtile * 64 + mt * 16 + kq * 4 + r;
                float ps = 0.f, pd = 0.f;
                #pragma unroll
                for (int nt = 0; nt < 4; nt++) {
                    ps = fmaf(acc[mt][nt][r], s_att[nt], ps);
                    pd = fmaf(acc[mt][nt][r], d_att[nt], pd);
                }
                #pragma unroll
                for (int msk = 1; msk < 16; msk <<= 1) {
                    ps += __shfl_xor(ps, msk);
                    pd += __shfl_xor(pd, msk);
                }
                if (c16 == 0 && row < M) {
                    asb[(size_t)row * nwt + hidx] = ps;
                    adb[(size_t)row * nwt + hidx] = pd;
                }
            }
        }
    }

    // ---- C write ----
    #pragma unroll
    for (int mt = 0; mt < 4; mt++) {
        #pragma unroll
        for (int r = 0; r < 4; r++) {
            int row = m0 + mtile * 64 + mt * 16 + kq * 4 + r;
            if (row >= M) continue;
            #pragma unroll
            for (int nt = 0; nt < 4; nt++) {
                int col = ntile * 64 + nt * 16 + c16;
                if (col >= N) continue;
                float v = acc[mt][nt][r];
                if (bias) v += bias[col];
                if (do_relu) v = fmaxf(v, 0.f);
                if (Cf) Cf[(size_t)row * N + col] = v;
                if (Chi) Chi[(size_t)row * N + col] = f2bf(v);
                if (Cext) {
                    unsigned short hh = f2bf(v);
                    unsigned short ll = f2bf(v - bf2f(hh));
                    size_t b = (size_t)row * (3 * N);
                    Cext[b + col] = hh;
                    Cext[b + N + col] = ll;
                    Cext[b + 2 * N + col] = hh;
                }
            }
        }
    }
}

__device__ __forceinline__ float wave_max_f(float v) {
    #pragma unroll
    for (int off = 32; off; off >>= 1) v = fmaxf(v, __shfl_xor(v, off));
    return v;
}
__device__ __forceinline__ float wave_sum_f(float v) {
    #pragma unroll
    for (int off = 32; off; off >>= 1) v += __shfl_xor(v, off);
    return v;
}

// ---------------------------------------------------------------------------
// Aggregation (verified r5/r6): one wave per node, all heads, bf16 gather.
// Output in split-ext layout [hi | lo | hi] (stride 192).
// ---------------------------------------------------------------------------
template <int H, bool MEAN_BN>
__global__ __launch_bounds__(256) void agg_k(
    const unsigned short* __restrict__ hfeat,   // [N, H*64] bf16
    const float* __restrict__ a_s, const float* __restrict__ a_d,
    const int* __restrict__ rowptr, const int* __restrict__ csr,
    const float* __restrict__ scale,   // MEAN_BN: folded BN scale; else unused
    const float* __restrict__ shift,   // MEAN_BN: folded BN shift; else bias
    unsigned short* __restrict__ outext, int N) {
    constexpr int OUT = H * 64;
    constexpr int F = H;
    constexpr int G = 64 / H;
    __shared__ float alpha_s[4][H][65];
    const int wv = threadIdx.x >> 6;
    const int lane = threadIdx.x & 63;
    const int node = blockIdx.x * 4 + wv;
    if (node >= N) return;        // no __syncthreads in this kernel — safe

    const int row = rowptr[node];
    const int deg = rowptr[node + 1] - row;
    const int hl = lane / G;

    float adn[H];
    #pragma unroll
    for (int h = 0; h < H; h++) adn[h] = a_d[(size_t)node * H + h];

    float acc[F] = {};

    if (deg <= 64) {
        int s = 0;
        float e[H];
        #pragma unroll
        for (int h = 0; h < H; h++) e[h] = -INFINITY;
        if (lane < deg) {
            s = csr[row + lane];
            const float* ap = a_s + (size_t)s * H;
            if constexpr (H >= 4) {
                #pragma unroll
                for (int h4 = 0; h4 < H; h4 += 4) {
                    float4 av = *(const float4*)(ap + h4);
                    e[h4 + 0] = av.x + adn[h4 + 0];
                    e[h4 + 1] = av.y + adn[h4 + 1];
                    e[h4 + 2] = av.z + adn[h4 + 2];
                    e[h4 + 3] = av.w + adn[h4 + 3];
                }
            } else {
                e[0] = ap[0] + adn[0];
            }
            #pragma unroll
            for (int h = 0; h < H; h++) e[h] = e[h] > 0.f ? e[h] : 0.2f * e[h];
        }
        float m[H], p[H], inv[H];
        #pragma unroll
        for (int h = 0; h < H; h++) m[h] = wave_max_f(e[h]);
        #pragma unroll
        for (int h = 0; h < H; h++) p[h] = (lane < deg) ? __expf(e[h] - m[h]) : 0.f;
        #pragma unroll
        for (int h = 0; h < H; h++) inv[h] = 1.f / (wave_sum_f(p[h]) + 1e-16f);
        if (lane < deg) {
            #pragma unroll
            for (int h = 0; h < H; h++) alpha_s[wv][h][lane] = p[h] * inv[h];
        }
        asm volatile("s_waitcnt lgkmcnt(0)" ::: "memory");
        for (int jj = 0; jj < deg; jj++) {
            int ss = __builtin_amdgcn_readlane(s, jj);
            float al = alpha_s[wv][hl][jj];
            const unsigned short* rp = hfeat + (size_t)ss * OUT + lane * F;
            if constexpr (F == 8) {
                u16x8_t u = *(const u16x8_t*)rp;
                #pragma unroll
                for (int i = 0; i < 8; i++) acc[i] = fmaf(al, bf2f(u[i]), acc[i]);
            } else if constexpr (F == 4) {
                u16x4_t u = *(const u16x4_t*)rp;
                #pragma unroll
                for (int i = 0; i < 4; i++) acc[i] = fmaf(al, bf2f(u[i]), acc[i]);
            } else {
                acc[0] = fmaf(al, bf2f(rp[0]), acc[0]);
            }
        }
    } else {
        float m[H];
        #pragma unroll
        for (int h = 0; h < H; h++) m[h] = -INFINITY;
        for (int c0 = 0; c0 < deg; c0 += 64) {
            int j = c0 + lane;
            if (j < deg) {
                int s2 = csr[row + j];
                #pragma unroll
                for (int h = 0; h < H; h++) {
                    float e = a_s[(size_t)s2 * H + h] + adn[h];
                    e = e > 0.f ? e : 0.2f * e;
                    m[h] = fmaxf(m[h], e);
                }
            }
        }
        #pragma unroll
        for (int h = 0; h < H; h++) m[h] = wave_max_f(m[h]);
        float dsum[H] = {};
        for (int c0 = 0; c0 < deg; c0 += 64) {
            int j = c0 + lane;
            if (j < deg) {
                int s2 = csr[row + j];
                #pragma unroll
                for (int h = 0; h < H; h++) {
                    float e = a_s[(size_t)s2 * H + h] + adn[h];
                    e = e > 0.f ? e : 0.2f * e;
                    dsum[h] += __expf(e - m[h]);
                }
            }
        }
        float inv[H];
        #pragma unroll
        for (int h = 0; h < H; h++) inv[h] = 1.f / (wave_sum_f(dsum[h]) + 1e-16f);
        for (int c0 = 0; c0 < deg; c0 += 64) {
            int j = c0 + lane;
            int cnt = min(64, deg - c0);
            int s = 0;
            if (j < deg) {
                s = csr[row + j];
                #pragma unroll
                for (int h = 0; h < H; h++) {
                    float e = a_s[(size_t)s * H + h] + adn[h];
                    e = e > 0.f ? e : 0.2f * e;
                    alpha_s[wv][h][lane] = __expf(e - m[h]) * inv[h];
                }
            }
            asm volatile("s_waitcnt lgkmcnt(0)" ::: "memory");
            for (int jj = 0; jj < cnt; jj++) {
                int ss = __builtin_amdgcn_readlane(s, jj);
                float al = alpha_s[wv][hl][jj];
                const unsigned short* rp = hfeat + (size_t)ss * OUT + lane * F;
                if constexpr (F == 8) {
                    u16x8_t u = *(const u16x8_t*)rp;
                    #pragma unroll
                    for (int i = 0; i < 8; i++) acc[i] = fmaf(al, bf2f(u[i]), acc[i]);
                } else if constexpr (F == 4) {
                    u16x4_t u = *(const u16x4_t*)rp;
                    #pragma unroll
                    for (int i = 0; i < 4; i++) acc[i] = fmaf(al, bf2f(u[i]), acc[i]);
                } else {
                    acc[0] = fmaf(al, bf2f(rp[0]), acc[0]);
                }
            }
            asm volatile("s_waitcnt lgkmcnt(0)" ::: "memory");
        }
    }

    if constexpr (MEAN_BN) {
        #pragma unroll
        for (int i = 0; i < F; i++) {
            #pragma unroll
            for (int msk = G; msk < 64; msk <<= 1)
                acc[i] += __shfl_xor(acc[i], msk);
        }
        if (lane < G) {
            int c0 = lane * F;
            size_t b = (size_t)node * 192;
            #pragma unroll
            for (int i = 0; i < F; i++) {
                float v = fmaf(acc[i] * (1.0f / H), scale[c0 + i], shift[c0 + i]);
                v = fmaxf(v, 0.f);
                unsigned short hh = f2bf(v);
                unsigned short ll = f2bf(v - bf2f(hh));
                outext[b + c0 + i] = hh;
                outext[b + 64 + c0 + i] = ll;
                outext[b + 128 + c0 + i] = hh;
            }
        }
    } else {
        float v = acc[0] + shift[lane];
        unsigned short hh = f2bf(v);
        unsigned short ll = f2bf(v - bf2f(hh));
        size_t b = (size_t)node * 192;
        outext[b + lane] = hh;
        outext[b + 64 + lane] = ll;
        outext[b + 128 + lane] = hh;
    }
}

// ---------------------------------------------------------------------------
// Softmax over N_CLS logits, wave per node.
// ---------------------------------------------------------------------------
__global__ __launch_bounds__(256) void softmax_k(const float* __restrict__ logits,
                                                 float* __restrict__ out, int N) {
    int lane = threadIdx.x & 63;
    int n = (blockIdx.x * blockDim.x + threadIdx.x) >> 6;
    if (n >= N) return;
    float lg = (lane < N_CLS) ? logits[(size_t)n * N_CLS + lane] : -INFINITY;
    float m = wave_max_f(lg);
    float p = (lane < N_CLS) ? __expf(lg - m) : 0.f;
    float s = wave_sum_f(p);
    if (lane < N_CLS) out[(size_t)n * N_CLS + lane] = p / s;
}

// ---------------------------------------------------------------------------
extern "C" void kernel_launch(void* const* d_in, const int* in_sizes, int n_in,
                              void* d_out, int out_size, void* d_ws, size_t ws_size,
                              hipStream_t stream) {
    const int N = NN, E = EE, E2 = EE + NN;
    const float* x    = (const float*)d_in[0];
    const int*   ei   = (const int*)d_in[1];
    const float* W1   = (const float*)d_in[2];
    const float* as1  = (const float*)d_in[3];
    const float* ad1  = (const float*)d_in[4];
    const float* b1   = (const float*)d_in[5];
    const float* W2   = (const float*)d_in[6];
    const float* as2  = (const float*)d_in[7];
    const float* ad2  = (const float*)d_in[8];
    const float* b2   = (const float*)d_in[9];
    const float* W3   = (const float*)d_in[10];
    const float* as3  = (const float*)d_in[11];
    const float* ad3  = (const float*)d_in[12];
    const float* b3   = (const float*)d_in[13];
    const float* bn1g = (const float*)d_in[14];
    const float* bn1b = (const float*)d_in[15];
    const float* bn1m = (const float*)d_in[16];
    const float* bn1v = (const float*)d_in[17];
    const float* bn2g = (const float*)d_in[18];
    const float* bn2b = (const float*)d_in[19];
    const float* bn2m = (const float*)d_in[20];
    const float* bn2v = (const float*)d_in[21];
    const float* cW1  = (const float*)d_in[22];
    const float* cb1  = (const float*)d_in[23];
    const float* cW2  = (const float*)d_in[24];
    const float* cb2  = (const float*)d_in[25];
    float* out = (float*)d_out;

    char* ws = (char*)d_ws;
    size_t off = 0;
    auto alloc = [&](size_t bytes) {
        void* p = ws + off;
        off = (off + bytes + 255) & ~(size_t)255;
        return p;
    };
    int*   rowptr = (int*)alloc((size_t)(N + 1) * 4);
    int*   cursor = (int*)alloc((size_t)N * 4);
    int*   excl   = (int*)alloc((size_t)N * 4);
    int*   bsum   = (int*)alloc(64 * 4);
    int*   csr    = (int*)alloc((size_t)E2 * 4);
    unsigned short* xext = (unsigned short*)alloc((size_t)N * 768 * 2);   // 76.8 MB
    unsigned short* hbf  = (unsigned short*)alloc((size_t)N * 512 * 2);   // 51.2 MB
    float* asb    = (float*)alloc((size_t)N * 8 * 4);
    float* adb    = (float*)alloc((size_t)N * 8 * 4);
    unsigned short* f1ext = (unsigned short*)alloc((size_t)N * 192 * 2);
    unsigned short* f2ext = (unsigned short*)alloc((size_t)N * 192 * 2);
    unsigned short* wext  = (unsigned short*)alloc((size_t)512 * 768 * 2);
    float* sc1 = (float*)alloc(64 * 4);
    float* sh1 = (float*)alloc(64 * 4);
    float* sc2 = (float*)alloc(64 * 4);
    float* sh2 = (float*)alloc(64 * 4);
    // aliases (stream-ordered, regions free by then):
    unsigned short* f3ext = f2ext;           // f2ext free after L3 gemm
    unsigned short* zext  = f1ext;           // f1ext free after L2 gemm
    float* logits = (float*)xext;            // xext free after L1 gemm

    const int NB = (N + 1023) / 1024;        // 49 scan blocks

    // ---- CSR build (parallel scan) + BN fold ----
    zero_k<<<(N + 255) / 256, 256, 0, stream>>>(cursor, N);
    count_k<<<(E2 + 255) / 256, 256, 0, stream>>>(ei, cursor, E, N);
    scan1_k<<<NB, 1024, 0, stream>>>(cursor, excl, bsum, N);
    scan2_k<<<1, 64, 0, stream>>>(bsum, NB);
    scan3_k<<<(N + 255) / 256, 256, 0, stream>>>(excl, bsum, rowptr, N, E2);
    zero_k<<<(N + 255) / 256, 256, 0, stream>>>(cursor, N);
    fill_k<<<(E2 + 255) / 256, 256, 0, stream>>>(ei, rowptr, cursor, csr, E, N);
    bnprep_k<<<1, 64, 0, stream>>>(bn1g, bn1b, bn1m, bn1v, b1, sc1, sh1);
    bnprep_k<<<1, 64, 0, stream>>>(bn2g, bn2b, bn2m, bn2v, b2, sc2, sh2);

    const int AB = (N + 3) / 4;

    // ---- Layer 1: heads=8, in=256 (KE=768, NT=512 -> lognwt=3, RT=64) ----
    cvt_a3_k<<<((size_t)N * 256 + 255) / 256, 256, 0, stream>>>(x, xext, N, 256);
    cvt_bt3_k<<<(256 * 512 + 255) / 256, 256, 0, stream>>>(W1, wext, 256, 512);
    gemm_ext_k<<<(N + 63) / 64, 512, 0, stream>>>(xext, wext, nullptr, hbf, nullptr,
        N, 512, 768, 3, nullptr, 0, as1, ad1, asb, adb);
    agg_k<8, true><<<AB, 256, 0, stream>>>(hbf, asb, adb, rowptr, csr, sc1, sh1, f1ext, N);

    // ---- Layer 2: heads=4, in=64 (KE=192, NT=256 -> lognwt=2, RT=128) ----
    cvt_bt3_k<<<(64 * 256 + 255) / 256, 256, 0, stream>>>(W2, wext, 64, 256);
    gemm_ext_k<<<(N + 127) / 128, 512, 0, stream>>>(f1ext, wext, nullptr, hbf, nullptr,
        N, 256, 192, 2, nullptr, 0, as2, ad2, asb, adb);
    agg_k<4, true><<<AB, 256, 0, stream>>>(hbf, asb, adb, rowptr, csr, sc2, sh2, f2ext, N);

    // ---- Layer 3: heads=1, in=64, concat (KE=192, NT=64 -> lognwt=0, RT=512) ----
    cvt_bt3_k<<<(64 * 64 + 255) / 256, 256, 0, stream>>>(W3, wext, 64, 64);
    gemm_ext_k<<<(N + 511) / 512, 512, 0, stream>>>(f2ext, wext, nullptr, hbf, nullptr,
        N, 64, 192, 0, nullptr, 0, as3, ad3, asb, adb);
    agg_k<1, false><<<AB, 256, 0, stream>>>(hbf, asb, adb, rowptr, csr, nullptr, b3, f3ext, N);

    // ---- Classifier: z = relu(f3@cW1+cb1) (ext out); logits; softmax ----
    cvt_bt3_k<<<(64 * 64 + 255) / 256, 256, 0, stream>>>(cW1, wext, 64, 64);
    gemm_ext_k<<<(N + 511) / 512, 512, 0, stream>>>(f3ext, wext, nullptr, nullptr, zext,
        N, 64, 192, 0, cb1, 1, nullptr, nullptr, nullptr, nullptr);
    cvt_bt3_k<<<(64 * N_CLS + 255) / 256, 256, 0, stream>>>(cW2, wext, 64, N_CLS);
    gemm_ext_k<<<(N + 511) / 512, 512, 0, stream>>>(zext, wext, logits, nullptr, nullptr,
        N, N_CLS, 192, 0, cb2, 0, nullptr, nullptr, nullptr, nullptr);
    softmax_k<<<(N + 3) / 4, 256, 0, stream>>>(logits, out, N);
}